// Round 6
// baseline (3249.155 us; speedup 1.0000x reference)
//
#include <hip/hip_runtime.h>

#define B_   128
#define S_   256
#define EMB_ 256
#define H_   1024
#define NH3  3072

#define G_      8     // batch groups
#define NW      32    // workgroups per group
#define MG      16    // batch rows per group
#define HS      32    // H columns per workgroup
#define THREADS 768   // 12 waves

typedef _Float16 f16;
typedef _Float16 h8 __attribute__((ext_vector_type(8)));
typedef float    f4 __attribute__((ext_vector_type(4)));
typedef unsigned int u32;

// ---------- gather + fp16 convert
__global__ void gather_kernel(const int* __restrict__ x, const float* __restrict__ emb,
                              f16* __restrict__ xe16) {
  int m = blockIdx.x, k = threadIdx.x;
  int b = m & 127, s = m >> 7;
  int row = x[b * S_ + s];
  xe16[m * EMB_ + k] = (f16)emb[row * EMB_ + k];
}

// ---------- transpose + fp16 convert: out[n*K + k] = (f16) in[k*N + n]
__global__ void transpose_cvt(const float* __restrict__ in, f16* __restrict__ out,
                              int K, int N) {
  __shared__ float tile[32][33];
  int n0 = blockIdx.x * 32, k0 = blockIdx.y * 32;
  int tx = threadIdx.x & 31, ty = threadIdx.x >> 5;
#pragma unroll
  for (int i = 0; i < 4; ++i)
    tile[ty + 8 * i][tx] = in[(k0 + ty + 8 * i) * N + n0 + tx];
  __syncthreads();
#pragma unroll
  for (int i = 0; i < 4; ++i)
    out[(n0 + ty + 8 * i) * K + k0 + tx] = (f16)tile[tx][ty + 8 * i];
}

// ---------- persistent GRU kernel: tagged-word exchange, no barriers
__launch_bounds__(THREADS, 3)
__global__ void gru_kernel(const f16* __restrict__ xe16, const f16* __restrict__ Ut,
                           const f16* __restrict__ Wt, const float* __restrict__ hidden,
                           const float* __restrict__ bvec, float* __restrict__ out,
                           u32* __restrict__ htag) {
  __shared__ f16   h_lds[MG * H_];        // 32 KB, rows of 2048B, XOR-swizzled
  __shared__ f16   xe_lds[2][MG * EMB_];  // 16 KB, rows of 512B, XOR-swizzled
  __shared__ float recS[4][MG][100];      // K-split partials: z[0..31] r[32..63] xh[64..95]
  __shared__ float recU[4][MG][36];       // K-split partials: rh[0..31]

  const int tid = threadIdx.x;
  const int bid = blockIdx.x;
  const int g   = bid & 7;
  const int w   = bid >> 3;         // 0..31
  const int gb0 = g * MG;
  const int hc0 = w * HS;

  const int lane = tid & 63;
  const int wv   = tid >> 6;        // 0..11
  const int ksp  = wv & 3;          // K quarter
  const int cp   = wv >> 2;         // gate 0=z 1=r 2=hh
  const int ln   = lane & 15;
  const int klo  = lane >> 4;
  const int bl   = tid >> 5;        // gate row (tid<512)
  const int jl   = tid & 31;

  // ---- weights register-resident: per wave one gate, 2 col-tiles, K-quarter
  h8 uf0[8], uf1[8], wf0[2], wf1[2];
  {
    const f16* u0 = Ut + (size_t)(cp * H_ + hc0 + ln) * H_ + ksp * 256 + klo * 8;
    const f16* u1 = u0 + (size_t)16 * H_;
#pragma unroll
    for (int kt = 0; kt < 8; ++kt) { uf0[kt] = *(const h8*)(u0 + kt * 32);
                                     uf1[kt] = *(const h8*)(u1 + kt * 32); }
    const f16* w0 = Wt + (size_t)(cp * H_ + hc0 + ln) * EMB_ + ksp * 64 + klo * 8;
    const f16* w1 = w0 + 16 * EMB_;
#pragma unroll
    for (int kt = 0; kt < 2; ++kt) { wf0[kt] = *(const h8*)(w0 + kt * 32);
                                     wf1[kt] = *(const h8*)(w1 + kt * 32); }
  }
#pragma unroll
  for (int kt = 0; kt < 8; ++kt) { asm volatile("" : "+v"(uf0[kt])); asm volatile("" : "+v"(uf1[kt])); }
  asm volatile("" : "+v"(wf0[0]), "+v"(wf0[1]), "+v"(wf1[0]), "+v"(wf1[1]));

  // ---- per-thread gate state: h + biases in registers
  float hprev = 0.f, bz = 0.f, brr = 0.f, bxh = 0.f, brh = 0.f;
  size_t obase = 0, soff = 0;
  if (tid < 512) {
    int col = hc0 + jl;
    bz  = bvec[col] + bvec[NH3 + col];
    brr = bvec[H_ + col] + bvec[NH3 + H_ + col];
    bxh = bvec[2 * H_ + col];
    brh = bvec[NH3 + 2 * H_ + col];
    hprev = hidden[(size_t)(gb0 + bl) * H_ + col];
    obase = ((size_t)(gb0 + bl) * S_) * H_ + col;
    soff  = (size_t)(gb0 + bl) * H_ + col;
  }

  // ---- stage h(0) from `hidden` (f32 -> f16, swizzled)
  for (int idx = tid; idx < MG * H_ / 4; idx += THREADS) {   // 4096 float4 chunks
    int r = idx >> 8, c4 = idx & 255;
    float4 hv = ((const float4*)(hidden + (size_t)(gb0 + r) * H_))[c4];
    unsigned lo = ((unsigned)__builtin_bit_cast(unsigned short, (f16)hv.y) << 16)
                |  (unsigned)__builtin_bit_cast(unsigned short, (f16)hv.x);
    unsigned hi = ((unsigned)__builtin_bit_cast(unsigned short, (f16)hv.w) << 16)
                |  (unsigned)__builtin_bit_cast(unsigned short, (f16)hv.z);
    uint2 pk = {lo, hi};
    *(uint2*)((char*)h_lds + r * 2048 + ((c4 * 8) ^ ((r & 7) << 4))) = pk;
  }
  // ---- stage xe(0)
  for (int idx = tid; idx < MG * EMB_ / 8; idx += THREADS) { // 512 chunks
    uint4 v = ((const uint4*)(xe16 + (size_t)gb0 * EMB_))[idx];
    int r = idx >> 5, c = idx & 31;
    *(uint4*)((char*)xe_lds[0] + r * 512 + ((c * 16) ^ ((r & 7) << 4))) = v;
  }
  __syncthreads();

  for (int t = 0; t < S_; ++t) {
    // ---- MFMA: U (16 MFMAs) + W (4) per wave, shared A-frags
    f4 a0 = {0.f,0.f,0.f,0.f}, a1 = {0.f,0.f,0.f,0.f};
    f4 a2 = {0.f,0.f,0.f,0.f}, a3 = {0.f,0.f,0.f,0.f};
    const char* hb = (const char*)h_lds + ln * 2048;
    const char* xb = (const char*)xe_lds[t & 1] + ln * 512;
    const int rm = (ln & 7) << 4;
#pragma unroll
    for (int kt = 0; kt < 8; ++kt) {
      h8 a = *(const h8*)(hb + ((ksp * 512 + kt * 64 + klo * 16) ^ rm));
      a0 = __builtin_amdgcn_mfma_f32_16x16x32_f16(a, uf0[kt], a0, 0, 0, 0);
      a1 = __builtin_amdgcn_mfma_f32_16x16x32_f16(a, uf1[kt], a1, 0, 0, 0);
    }
#pragma unroll
    for (int kt = 0; kt < 2; ++kt) {
      h8 aw = *(const h8*)(xb + ((ksp * 128 + kt * 64 + klo * 16) ^ rm));
      a2 = __builtin_amdgcn_mfma_f32_16x16x32_f16(aw, wf0[kt], a2, 0, 0, 0);
      a3 = __builtin_amdgcn_mfma_f32_16x16x32_f16(aw, wf1[kt], a3, 0, 0, 0);
    }
#pragma unroll
    for (int j = 0; j < 4; ++j) {
      int r = klo * 4 + j;
      if (cp < 2) {
        recS[ksp][r][cp * 32 + ln]      = a0[j] + a2[j];
        recS[ksp][r][cp * 32 + 16 + ln] = a1[j] + a3[j];
      } else {
        recS[ksp][r][64 + ln] = a2[j];
        recS[ksp][r][80 + ln] = a3[j];
        recU[ksp][r][ln]      = a0[j];
        recU[ksp][r][16 + ln] = a1[j];
      }
    }
    __syncthreads();

    // ---- gates (f32, h state in registers); tagged fire-and-forget publish
    float outv = 0.f;
    if (tid < 512) {
      float az = recS[0][bl][jl] + recS[1][bl][jl] + recS[2][bl][jl] + recS[3][bl][jl] + bz;
      float ar = recS[0][bl][32+jl] + recS[1][bl][32+jl] + recS[2][bl][32+jl] + recS[3][bl][32+jl] + brr;
      float xh = recS[0][bl][64+jl] + recS[1][bl][64+jl] + recS[2][bl][64+jl] + recS[3][bl][64+jl] + bxh;
      float rhu = recU[0][bl][jl] + recU[1][bl][jl] + recU[2][bl][jl] + recU[3][bl][jl] + brh;
      float z  = 1.f / (1.f + __expf(-az));
      float r  = 1.f / (1.f + __expf(-ar));
      float hh = 1.f - 2.f / (1.f + __expf(2.f * (xh + r * rhu)));
      float hn = z * hprev + (1.f - z) * hh;
      hprev = hn; outv = hn;
      if (t < S_ - 1) {
        u32 word = ((u32)(t + 1) << 16)
                 | (u32)__builtin_bit_cast(unsigned short, (f16)hn);
        __hip_atomic_store(htag + (size_t)((t + 1) % 3) * (B_ * H_) + soff, word,
                           __ATOMIC_RELAXED, __HIP_MEMORY_SCOPE_AGENT);
      }
      out[obase + (size_t)t * H_] = outv;
    }
    if (t == S_ - 1) {
      if (tid < 512) out[(size_t)B_ * S_ * H_ + soff] = outv;
      break;
    }

    // ---- exchange: tid<512 pull h(t+1) (tag-spin); tid>=512 stage xe(t+1)
    if (tid >= 512) {
      const uint4* src = (const uint4*)(xe16 + ((size_t)(t + 1) * B_ + gb0) * EMB_);
      char* dst = (char*)xe_lds[(t + 1) & 1];
#pragma unroll
      for (int i = 0; i < 2; ++i) {
        int idx = (tid - 512) * 2 + i;
        uint4 v = src[idx];
        int r = idx >> 5, c = idx & 31;
        *(uint4*)(dst + r * 512 + ((c * 16) ^ ((r & 7) << 4))) = v;
      }
    } else {
      const u32* src = htag + ((size_t)((t + 1) % 3) * B_ + gb0) * H_ + (tid << 1);
      const u32 tg = (u32)(t + 1);
      u32 va[16], vb[16];
#pragma unroll
      for (int r = 0; r < 16; ++r) {
        va[r] = __hip_atomic_load(src + r * H_,     __ATOMIC_RELAXED, __HIP_MEMORY_SCOPE_AGENT);
        vb[r] = __hip_atomic_load(src + r * H_ + 1, __ATOMIC_RELAXED, __HIP_MEMORY_SCOPE_AGENT);
      }
#pragma unroll
      for (int r = 0; r < 16; ++r) {
        while ((va[r] >> 16) != tg)
          va[r] = __hip_atomic_load(src + r * H_,     __ATOMIC_RELAXED, __HIP_MEMORY_SCOPE_AGENT);
        while ((vb[r] >> 16) != tg)
          vb[r] = __hip_atomic_load(src + r * H_ + 1, __ATOMIC_RELAXED, __HIP_MEMORY_SCOPE_AGENT);
        u32 pk = (va[r] & 0xffffu) | (vb[r] << 16);
        *(u32*)((char*)h_lds + r * 2048 + ((tid * 4) ^ ((r & 7) << 4))) = pk;
      }
    }
    __syncthreads();
  }
}

extern "C" void kernel_launch(void* const* d_in, const int* in_sizes, int n_in,
                              void* d_out, int out_size, void* d_ws, size_t ws_size,
                              hipStream_t stream) {
  const int*   x      = (const int*)  d_in[0];
  const float* hidden = (const float*)d_in[1];
  const float* emb    = (const float*)d_in[2];
  const float* W      = (const float*)d_in[3];
  const float* U      = (const float*)d_in[4];
  const float* bvec   = (const float*)d_in[5];
  float* out = (float*)d_out;

  char* ws = (char*)d_ws;
  f16* Ut    = (f16*)(ws);                   //  6,291,456 B
  f16* Wt    = (f16*)(ws + 6291456);         //  1,572,864 B
  f16* xe16  = (f16*)(ws + 7864320);         // 16,777,216 B
  u32* htag  = (u32*)(ws + 24641536);        //  1,572,864 B (3 tagged buffers)

  hipMemsetAsync(htag, 0, 3 * B_ * H_ * 4, stream);
  hipLaunchKernelGGL(transpose_cvt, dim3(NH3 / 32, H_ / 32), dim3(256), 0, stream,
                     U, Ut, H_, NH3);
  hipLaunchKernelGGL(transpose_cvt, dim3(NH3 / 32, EMB_ / 32), dim3(256), 0, stream,
                     W, Wt, EMB_, NH3);
  hipLaunchKernelGGL(gather_kernel, dim3(B_ * S_), dim3(EMB_), 0, stream, x, emb, xe16);

  void* args[] = { (void*)&xe16, (void*)&Ut, (void*)&Wt, (void*)&hidden,
                   (void*)&bvec, (void*)&out, (void*)&htag };
  hipLaunchCooperativeKernel(reinterpret_cast<void*>(gru_kernel),
                             dim3(G_ * NW), dim3(THREADS), args, 0, stream);
}

// Round 7
// 861.034 us; speedup vs baseline: 3.7736x; 3.7736x over previous
//
#include <hip/hip_runtime.h>

#define B_   128
#define S_   256
#define EMB_ 256
#define H_   1024
#define NH3  3072

#define G_      8     // batch groups
#define NW      32    // workgroups per group
#define MG      16    // batch rows per group
#define HS      32    // H columns per workgroup
#define THREADS 768   // 12 waves

typedef _Float16 f16;
typedef _Float16 h8 __attribute__((ext_vector_type(8)));
typedef float    f4 __attribute__((ext_vector_type(4)));
typedef unsigned long long u64;

// ---------- gather + fp16 convert
__global__ void gather_kernel(const int* __restrict__ x, const float* __restrict__ emb,
                              f16* __restrict__ xe16) {
  int m = blockIdx.x, k = threadIdx.x;
  int b = m & 127, s = m >> 7;
  int row = x[b * S_ + s];
  xe16[m * EMB_ + k] = (f16)emb[row * EMB_ + k];
}

// ---------- transpose + fp16 convert: out[n*K + k] = (f16) in[k*N + n]
__global__ void transpose_cvt(const float* __restrict__ in, f16* __restrict__ out,
                              int K, int N) {
  __shared__ float tile[32][33];
  int n0 = blockIdx.x * 32, k0 = blockIdx.y * 32;
  int tx = threadIdx.x & 31, ty = threadIdx.x >> 5;
#pragma unroll
  for (int i = 0; i < 4; ++i)
    tile[ty + 8 * i][tx] = in[(k0 + ty + 8 * i) * N + n0 + tx];
  __syncthreads();
#pragma unroll
  for (int i = 0; i < 4; ++i)
    out[(n0 + ty + 8 * i) * K + k0 + tx] = (f16)tile[tx][ty + 8 * i];
}

// ---------- persistent GRU kernel (round-5 protocol, flags instead of counter)
__launch_bounds__(THREADS, 3)
__global__ void gru_kernel(const f16* __restrict__ xe16, const f16* __restrict__ Ut,
                           const f16* __restrict__ Wt, const float* __restrict__ hidden,
                           const float* __restrict__ bvec, float* __restrict__ out,
                           f16* __restrict__ h16, int* __restrict__ flags) {
  __shared__ f16   h_lds[MG * H_];        // 32 KB, rows of 2048B, XOR-swizzled
  __shared__ f16   xe_lds[2][MG * EMB_];  // 16 KB, rows of 512B, XOR-swizzled
  __shared__ float recS[4][MG][100];      // K-split partials: z[0..31] r[32..63] xh[64..95]
  __shared__ float recU[4][MG][36];       // K-split partials: rh[0..31]

  const int tid = threadIdx.x;
  const int bid = blockIdx.x;
  const int g   = bid & 7;
  const int w   = bid >> 3;         // 0..31
  const int gb0 = g * MG;
  const int hc0 = w * HS;

  const int lane = tid & 63;
  const int wv   = tid >> 6;        // 0..11
  const int ksp  = wv & 3;          // K quarter
  const int cp   = wv >> 2;         // gate 0=z 1=r 2=hh
  const int ln   = lane & 15;
  const int klo  = lane >> 4;
  const int bl   = tid >> 5;        // gate row (tid<512)
  const int jl   = tid & 31;

  int* gflags = flags + g * NW;

  // ---- weights register-resident: per wave one gate, 2 col-tiles, K-quarter
  h8 uf0[8], uf1[8], wf0[2], wf1[2];
  {
    const f16* u0 = Ut + (size_t)(cp * H_ + hc0 + ln) * H_ + ksp * 256 + klo * 8;
    const f16* u1 = u0 + (size_t)16 * H_;
#pragma unroll
    for (int kt = 0; kt < 8; ++kt) { uf0[kt] = *(const h8*)(u0 + kt * 32);
                                     uf1[kt] = *(const h8*)(u1 + kt * 32); }
    const f16* w0 = Wt + (size_t)(cp * H_ + hc0 + ln) * EMB_ + ksp * 64 + klo * 8;
    const f16* w1 = w0 + 16 * EMB_;
#pragma unroll
    for (int kt = 0; kt < 2; ++kt) { wf0[kt] = *(const h8*)(w0 + kt * 32);
                                     wf1[kt] = *(const h8*)(w1 + kt * 32); }
  }
#pragma unroll
  for (int kt = 0; kt < 8; ++kt) { asm volatile("" : "+v"(uf0[kt])); asm volatile("" : "+v"(uf1[kt])); }
  asm volatile("" : "+v"(wf0[0]), "+v"(wf0[1]), "+v"(wf1[0]), "+v"(wf1[1]));

  // ---- per-thread gate state: h + biases in registers
  float hprev = 0.f, bz = 0.f, brr = 0.f, bxh = 0.f, brh = 0.f;
  size_t obase = 0, soff = 0;
  if (tid < 512) {
    int col = hc0 + jl;
    bz  = bvec[col] + bvec[NH3 + col];
    brr = bvec[H_ + col] + bvec[NH3 + H_ + col];
    bxh = bvec[2 * H_ + col];
    brh = bvec[NH3 + 2 * H_ + col];
    hprev = hidden[(size_t)(gb0 + bl) * H_ + col];
    obase = ((size_t)(gb0 + bl) * S_) * H_ + col;
    soff  = (size_t)(gb0 + bl) * H_ + col;
  }

  // ---- stage h(0) from `hidden` (f32 -> f16, swizzled); no cross-WG sync needed
  for (int idx = tid; idx < MG * H_ / 4; idx += THREADS) {   // 4096 float4 chunks
    int r = idx >> 8, c4 = idx & 255;
    float4 hv = ((const float4*)(hidden + (size_t)(gb0 + r) * H_))[c4];
    unsigned lo = ((unsigned)__builtin_bit_cast(unsigned short, (f16)hv.y) << 16)
                |  (unsigned)__builtin_bit_cast(unsigned short, (f16)hv.x);
    unsigned hi = ((unsigned)__builtin_bit_cast(unsigned short, (f16)hv.w) << 16)
                |  (unsigned)__builtin_bit_cast(unsigned short, (f16)hv.z);
    uint2 pk = {lo, hi};
    *(uint2*)((char*)h_lds + r * 2048 + ((c4 * 8) ^ ((r & 7) << 4))) = pk;
  }
  // ---- stage xe(0)
  for (int idx = tid; idx < MG * EMB_ / 8; idx += THREADS) { // 512 chunks
    uint4 v = ((const uint4*)(xe16 + (size_t)gb0 * EMB_))[idx];
    int r = idx >> 5, c = idx & 31;
    *(uint4*)((char*)xe_lds[0] + r * 512 + ((c * 16) ^ ((r & 7) << 4))) = v;
  }
  __syncthreads();

  for (int t = 0; t < S_; ++t) {
    // ---- pull h(t) slab (32 KB) via agent-scope atomic loads (proven path)
    if (t > 0) {
      const u64* src = (const u64*)(h16 + (size_t)(t & 1) * (B_ * H_) + (size_t)gb0 * H_);
      u64 v0 = __hip_atomic_load(src + tid,               __ATOMIC_RELAXED, __HIP_MEMORY_SCOPE_AGENT);
      u64 v1 = __hip_atomic_load(src + tid + THREADS,     __ATOMIC_RELAXED, __HIP_MEMORY_SCOPE_AGENT);
      u64 v2 = __hip_atomic_load(src + tid + 2 * THREADS, __ATOMIC_RELAXED, __HIP_MEMORY_SCOPE_AGENT);
      u64 v3 = __hip_atomic_load(src + tid + 3 * THREADS, __ATOMIC_RELAXED, __HIP_MEMORY_SCOPE_AGENT);
      u64 v4 = __hip_atomic_load(src + tid + 4 * THREADS, __ATOMIC_RELAXED, __HIP_MEMORY_SCOPE_AGENT);
      u64 v5 = 0;
      if (tid < 256)
        v5 = __hip_atomic_load(src + 3840 + tid, __ATOMIC_RELAXED, __HIP_MEMORY_SCOPE_AGENT);
      { int idx = tid;               int r = idx >> 8, c = idx & 255;
        *(u64*)((char*)h_lds + r * 2048 + ((c * 8) ^ ((r & 7) << 4))) = v0; }
      { int idx = tid + THREADS;     int r = idx >> 8, c = idx & 255;
        *(u64*)((char*)h_lds + r * 2048 + ((c * 8) ^ ((r & 7) << 4))) = v1; }
      { int idx = tid + 2 * THREADS; int r = idx >> 8, c = idx & 255;
        *(u64*)((char*)h_lds + r * 2048 + ((c * 8) ^ ((r & 7) << 4))) = v2; }
      { int idx = tid + 3 * THREADS; int r = idx >> 8, c = idx & 255;
        *(u64*)((char*)h_lds + r * 2048 + ((c * 8) ^ ((r & 7) << 4))) = v3; }
      { int idx = tid + 4 * THREADS; int r = idx >> 8, c = idx & 255;
        *(u64*)((char*)h_lds + r * 2048 + ((c * 8) ^ ((r & 7) << 4))) = v4; }
      if (tid < 256) {
        int idx = 3840 + tid;        int r = idx >> 8, c = idx & 255;
        *(u64*)((char*)h_lds + r * 2048 + ((c * 8) ^ ((r & 7) << 4))) = v5;
      }
      __syncthreads();
    }

    // ---- MFMA: U (16 MFMAs) + W (4) per wave, shared A-frags
    f4 a0 = {0.f,0.f,0.f,0.f}, a1 = {0.f,0.f,0.f,0.f};
    f4 a2 = {0.f,0.f,0.f,0.f}, a3 = {0.f,0.f,0.f,0.f};
    const char* hb = (const char*)h_lds + ln * 2048;
    const char* xb = (const char*)xe_lds[t & 1] + ln * 512;
    const int rm = (ln & 7) << 4;
#pragma unroll
    for (int kt = 0; kt < 8; ++kt) {
      h8 a = *(const h8*)(hb + ((ksp * 512 + kt * 64 + klo * 16) ^ rm));
      a0 = __builtin_amdgcn_mfma_f32_16x16x32_f16(a, uf0[kt], a0, 0, 0, 0);
      a1 = __builtin_amdgcn_mfma_f32_16x16x32_f16(a, uf1[kt], a1, 0, 0, 0);
    }
#pragma unroll
    for (int kt = 0; kt < 2; ++kt) {
      h8 aw = *(const h8*)(xb + ((ksp * 128 + kt * 64 + klo * 16) ^ rm));
      a2 = __builtin_amdgcn_mfma_f32_16x16x32_f16(aw, wf0[kt], a2, 0, 0, 0);
      a3 = __builtin_amdgcn_mfma_f32_16x16x32_f16(aw, wf1[kt], a3, 0, 0, 0);
    }
#pragma unroll
    for (int j = 0; j < 4; ++j) {
      int r = klo * 4 + j;
      if (cp < 2) {
        recS[ksp][r][cp * 32 + ln]      = a0[j] + a2[j];
        recS[ksp][r][cp * 32 + 16 + ln] = a1[j] + a3[j];
      } else {
        recS[ksp][r][64 + ln] = a2[j];
        recS[ksp][r][80 + ln] = a3[j];
        recU[ksp][r][ln]      = a0[j];
        recU[ksp][r][16 + ln] = a1[j];
      }
    }
    __syncthreads();

    // ---- gates (f32, h state in registers)
    float outv = 0.f;
    if (tid < 512) {
      float az = recS[0][bl][jl] + recS[1][bl][jl] + recS[2][bl][jl] + recS[3][bl][jl] + bz;
      float ar = recS[0][bl][32+jl] + recS[1][bl][32+jl] + recS[2][bl][32+jl] + recS[3][bl][32+jl] + brr;
      float xh = recS[0][bl][64+jl] + recS[1][bl][64+jl] + recS[2][bl][64+jl] + recS[3][bl][64+jl] + bxh;
      float rhu = recU[0][bl][jl] + recU[1][bl][jl] + recU[2][bl][jl] + recU[3][bl][jl] + brh;
      float z  = 1.f / (1.f + __expf(-az));
      float r  = 1.f / (1.f + __expf(-ar));
      float hh = 1.f - 2.f / (1.f + __expf(2.f * (xh + r * rhu)));
      float hn = z * hprev + (1.f - z) * hh;
      hprev = hn; outv = hn;
      if (t < S_ - 1) {
        unsigned short hb16 = __builtin_bit_cast(unsigned short, (f16)hn);
        __hip_atomic_store((unsigned short*)(h16 + (size_t)((t + 1) & 1) * (B_ * H_)) + soff,
                           hb16, __ATOMIC_RELAXED, __HIP_MEMORY_SCOPE_AGENT);
      }
    }
    if (t == S_ - 1) {
      if (tid < 512) {
        out[obase + (size_t)t * H_] = outv;
        out[(size_t)B_ * S_ * H_ + soff] = outv;
      }
      break;
    }

    // ---- drain own h-stores, then per-producer flag publish (no RMW)
    asm volatile("s_waitcnt vmcnt(0)" ::: "memory");
    __syncthreads();
    if (tid == 0)
      __hip_atomic_store(&gflags[w], t + 1, __ATOMIC_RELAXED, __HIP_MEMORY_SCOPE_AGENT);

    // ---- spin window: deferred out stores + xe(t+1) staging; wave 0 polls flags
    if (tid < 512) {
      out[obase + (size_t)t * H_] = outv;
    } else {
      const uint4* src = (const uint4*)(xe16 + ((size_t)(t + 1) * B_ + gb0) * EMB_);
      char* dst = (char*)xe_lds[(t + 1) & 1];
#pragma unroll
      for (int i = 0; i < 2; ++i) {
        int idx = (tid - 512) * 2 + i;
        uint4 v = src[idx];
        int r = idx >> 5, c = idx & 31;
        *(uint4*)(dst + r * 512 + ((c * 16) ^ ((r & 7) << 4))) = v;
      }
    }
    if (wv == 0) {
      const int need = t + 1;
      for (;;) {
        int f = __hip_atomic_load(&gflags[lane & 31], __ATOMIC_RELAXED, __HIP_MEMORY_SCOPE_AGENT);
        if (__all(f >= need)) break;
      }
    }
    __syncthreads();
  }
}

extern "C" void kernel_launch(void* const* d_in, const int* in_sizes, int n_in,
                              void* d_out, int out_size, void* d_ws, size_t ws_size,
                              hipStream_t stream) {
  const int*   x      = (const int*)  d_in[0];
  const float* hidden = (const float*)d_in[1];
  const float* emb    = (const float*)d_in[2];
  const float* W      = (const float*)d_in[3];
  const float* U      = (const float*)d_in[4];
  const float* bvec   = (const float*)d_in[5];
  float* out = (float*)d_out;

  char* ws = (char*)d_ws;
  f16* Ut    = (f16*)(ws);                   //  6,291,456 B
  f16* Wt    = (f16*)(ws + 6291456);         //  1,572,864 B
  f16* xe16  = (f16*)(ws + 7864320);         // 16,777,216 B
  f16* h16   = (f16*)(ws + 24641536);        //    524,288 B (double buffer)
  int* flags = (int*)(ws + 25165824);        //  8*32*4 = 1024 B

  hipMemsetAsync(flags, 0, 1024, stream);
  hipLaunchKernelGGL(transpose_cvt, dim3(NH3 / 32, H_ / 32), dim3(256), 0, stream,
                     U, Ut, H_, NH3);
  hipLaunchKernelGGL(transpose_cvt, dim3(NH3 / 32, EMB_ / 32), dim3(256), 0, stream,
                     W, Wt, EMB_, NH3);
  hipLaunchKernelGGL(gather_kernel, dim3(B_ * S_), dim3(EMB_), 0, stream, x, emb, xe16);

  void* args[] = { (void*)&xe16, (void*)&Ut, (void*)&Wt, (void*)&hidden,
                   (void*)&bvec, (void*)&out, (void*)&h16, (void*)&flags };
  hipLaunchCooperativeKernel(reinterpret_cast<void*>(gru_kernel),
                             dim3(G_ * NW), dim3(THREADS), args, 0, stream);
}